// Round 10
// baseline (287.236 us; speedup 1.0000x reference)
//
#include <hip/hip_runtime.h>
#include <hip/hip_bf16.h>

#define N_NODES 100000
#define N_EDGES 1600000
#define NBUCKET 782                 // ceil(100000 / 128) coarse buckets (dst >> 7)
#define NBLK 320                    // edge chunks (>= CU count for occupancy)
#define CHUNK_E 5000                // 320 * 5000 = 1.6M exactly
#define T2 (NBUCKET * NBLK)         // 250240
#define NCH2 ((T2 + 511) / 512)     // 489 (<= 512 for single-block scan_off)

typedef short v8s __attribute__((ext_vector_type(8)));
typedef float v4f __attribute__((ext_vector_type(4)));

static __device__ __forceinline__ unsigned pack_bf2(float a, float b) {
    __hip_bfloat162 p = __float22bfloat162_rn(make_float2(a, b));
    return *reinterpret_cast<unsigned*>(&p);
}
static __device__ __forceinline__ float2 bf2_to_f2(unsigned u) {
    __hip_bfloat162 p = *reinterpret_cast<__hip_bfloat162*>(&u);
    return __bfloat1622float2(p);
}

// ---------- prep: transpose W -> Wt[n][k] bf16 (once, tiny) ----------
__global__ __launch_bounds__(256) void prep_w(const float* __restrict__ W1,
                                              const float* __restrict__ W2,
                                              short* __restrict__ wt1,   // [64][128]
                                              short* __restrict__ wt2) { // [64][64]
    const int t = threadIdx.x;
    for (int i = t; i < 64 * 128; i += 256) {
        const int c = i >> 7, k = i & 127;
        wt1[i] = (short)(pack_bf2(W1[k * 64 + c], 0.f) & 0xFFFF);
    }
    for (int i = t; i < 64 * 64; i += 256) {
        const int c = i >> 6, k = i & 63;
        wt2[i] = (short)(pack_bf2(W2[k * 64 + c], 0.f) & 0xFFFF);
    }
}

// ---------- MFMA GEMM: outp_bf16[M,64] = in[M,K] @ W[K,64] ----------
template<int K, bool IN_BF>
__global__ __launch_bounds__(256) void gemm_mfma(const void* __restrict__ in,
                                                 const short* __restrict__ wt,  // [64][K] bf16
                                                 unsigned* __restrict__ outp) { // bf162 [node][32]
    __shared__ unsigned xs[64][K / 2 + 4];
    __shared__ unsigned ws[64][K / 2 + 4];
    const int t = threadIdx.x;
    const int row0 = blockIdx.x * 64;
    {
        const uint2* g = (const uint2*)wt;
        for (int i = t; i < 64 * K / 4; i += 256) {
            const int r = i / (K / 4), cu = i % (K / 4);
            ((uint2*)&ws[r][0])[cu] = g[i];
        }
    }
    if (IN_BF) {
        const uint2* g = (const uint2*)in;
        for (int i = t; i < 64 * K / 4; i += 256) {
            const int r = i / (K / 4), cu = i % (K / 4);
            const int row = row0 + r;
            uint2 v = make_uint2(0u, 0u);
            if (row < N_NODES) v = g[(size_t)row * (K / 4) + cu];
            ((uint2*)&xs[r][0])[cu] = v;
        }
    } else {
        const float4* g = (const float4*)in;
        for (int i = t; i < 64 * K / 4; i += 256) {
            const int r = i / (K / 4), cu = i % (K / 4);
            const int row = row0 + r;
            uint2 v = make_uint2(0u, 0u);
            if (row < N_NODES) {
                float4 f = g[(size_t)row * (K / 4) + cu];
                v.x = pack_bf2(f.x, f.y);
                v.y = pack_bf2(f.z, f.w);
            }
            ((uint2*)&xs[r][0])[cu] = v;
        }
    }
    __syncthreads();
    const int w = t >> 6;
    const int lane = t & 63;
    const int l15 = lane & 15;
    const int quad = lane >> 4;
    v4f acc[4];
#pragma unroll
    for (int tt = 0; tt < 4; ++tt) acc[tt] = (v4f){0.f, 0.f, 0.f, 0.f};
#pragma unroll
    for (int k0 = 0; k0 < K; k0 += 32) {
        const int ku = k0 / 2 + quad * 4;
        const v8s xb = *(const v8s*)&xs[w * 16 + l15][ku];   // B: n=node
#pragma unroll
        for (int tt = 0; tt < 4; ++tt) {
            const v8s wa = *(const v8s*)&ws[16 * tt + l15][ku];  // A: m=out col
            acc[tt] = __builtin_amdgcn_mfma_f32_16x16x32_bf16(wa, xb, acc[tt], 0, 0, 0);
        }
    }
    const int node = row0 + w * 16 + l15;
    if (node < N_NODES) {
#pragma unroll
        for (int tt = 0; tt < 4; ++tt) {
            uint2 o;
            o.x = pack_bf2(acc[tt][0], acc[tt][1]);
            o.y = pack_bf2(acc[tt][2], acc[tt][3]);
            *(uint2*)&outp[(size_t)node * 32 + 8 * tt + 2 * quad] = o;
        }
    }
}

// ---------- S1: per-(block,bucket) coarse histogram ----------
__global__ __launch_bounds__(256) void s1_hist(const int* __restrict__ dst,
                                               int* __restrict__ bh) {
    __shared__ int hist[NBUCKET];
    const int t = threadIdx.x;
    for (int i = t; i < NBUCKET; i += 256) hist[i] = 0;
    __syncthreads();
    const int e0 = blockIdx.x * CHUNK_E;
    for (int i = t; i < CHUNK_E; i += 256)
        atomicAdd(&hist[dst[e0 + i] >> 7], 1);
    __syncthreads();
    for (int i = t; i < NBUCKET; i += 256)
        bh[i * NBLK + blockIdx.x] = hist[i];
}

// ---------- S2: 3-phase exclusive scan of bh[T2] -> bh_ex ----------
__global__ __launch_bounds__(256) void scan_sums(const int* __restrict__ v,
                                                 int* __restrict__ csum, int n) {
    __shared__ int red[256];
    const int t = threadIdx.x;
    const int i0 = blockIdx.x * 512 + 2 * t;
    int a = (i0 < n) ? v[i0] : 0;
    int b = (i0 + 1 < n) ? v[i0 + 1] : 0;
    red[t] = a + b;
    __syncthreads();
    for (int off = 128; off > 0; off >>= 1) {
        if (t < off) red[t] += red[t + off];
        __syncthreads();
    }
    if (t == 0) csum[blockIdx.x] = red[0];
}

__global__ __launch_bounds__(512) void scan_off(const int* __restrict__ csum,
                                                int* __restrict__ coff, int nch) {
    __shared__ int part[512];
    const int t = threadIdx.x;
    int v = (t < nch) ? csum[t] : 0;
    part[t] = v;
    __syncthreads();
    for (int off = 1; off < 512; off <<= 1) {
        int u = (t >= off) ? part[t - off] : 0;
        __syncthreads();
        part[t] += u;
        __syncthreads();
    }
    if (t < nch) coff[t] = part[t] - v;   // exclusive
}

__global__ __launch_bounds__(256) void scan_apply(const int* __restrict__ v,
                                                  const int* __restrict__ coff,
                                                  int* __restrict__ vex, int n) {
    __shared__ int part[256];
    const int t = threadIdx.x;
    const int i0 = blockIdx.x * 512 + 2 * t;
    int a = (i0 < n) ? v[i0] : 0;
    int b = (i0 + 1 < n) ? v[i0 + 1] : 0;
    int pair = a + b;
    part[t] = pair;
    __syncthreads();
    for (int off = 1; off < 256; off <<= 1) {
        int u = (t >= off) ? part[t - off] : 0;
        __syncthreads();
        part[t] += u;
        __syncthreads();
    }
    const int e0 = coff[blockIdx.x] + part[t] - pair;
    if (i0 < n)     vex[i0] = e0;
    if (i0 + 1 < n) vex[i0 + 1] = e0 + a;
}

// ---------- S3: scatter edges into coarse buckets ----------
__global__ __launch_bounds__(256) void s3_scatter(const int* __restrict__ src,
                                                  const int* __restrict__ dst,
                                                  const float* __restrict__ w,
                                                  const int* __restrict__ bh_ex,
                                                  int2* __restrict__ coarse) {
    __shared__ int cur[NBUCKET];
    const int t = threadIdx.x;
    for (int i = t; i < NBUCKET; i += 256) cur[i] = bh_ex[i * NBLK + blockIdx.x];
    __syncthreads();
    const int e0 = blockIdx.x * CHUNK_E;
    for (int i = t; i < CHUNK_E; i += 256) {
        const int e = e0 + i;
        const int d = dst[e];
        const int pos = atomicAdd(&cur[d >> 7], 1);
        int2 ev;
        ev.x = src[e] | ((d & 127) << 17);   // src < 2^17
        ev.y = __float_as_int(w[e]);
        coarse[pos] = ev;
    }
}

// ---------- S4: per-bucket fine sort (128 nodes) + row_ptr; emits 4B records ----------
// record = src(17 bits) | wq(15 bits, w*32767 fixed point)
__global__ __launch_bounds__(256) void s4_fine(const int2* __restrict__ coarse,
                                               const int* __restrict__ bh_ex,
                                               unsigned* __restrict__ edge_sorted,
                                               int* __restrict__ row_ptr) {
    __shared__ int hist[128];
    __shared__ int part[128];
    __shared__ int cursor[128];
    const int b = blockIdx.x;
    const int t = threadIdx.x;
    const int beg = bh_ex[b * NBLK];
    const int end = (b + 1 < NBUCKET) ? bh_ex[(b + 1) * NBLK] : N_EDGES;
    if (t < 128) hist[t] = 0;
    __syncthreads();
    for (int i = beg + t; i < end; i += 256)
        atomicAdd(&hist[(coarse[i].x >> 17) & 127], 1);
    __syncthreads();
    if (t < 128) part[t] = hist[t];
    __syncthreads();
    for (int off = 1; off < 128; off <<= 1) {
        int u = 0;
        if (t < 128 && t >= off) u = part[t - off];
        __syncthreads();
        if (t < 128) part[t] += u;
        __syncthreads();
    }
    if (t < 128) {
        const int excl = beg + part[t] - hist[t];
        cursor[t] = excl;
        const int node = b * 128 + t;
        if (node < N_NODES) row_ptr[node] = excl;
    }
    if (b == NBUCKET - 1 && t == 0) row_ptr[N_NODES] = N_EDGES;
    __syncthreads();
    for (int i = beg + t; i < end; i += 256) {
        const int2 ev = coarse[i];
        const int f = (ev.x >> 17) & 127;
        const int pos = atomicAdd(&cursor[f], 1);
        const float wf = __int_as_float(ev.y);
        unsigned wq = (unsigned)__float2uint_rn(wf * 32767.f);
        wq = min(wq, 32767u);
        edge_sorted[pos] = (unsigned)(ev.x & 0x1FFFF) | (wq << 17);
    }
}

// ---------- Gather step: 8 edges, 8 lanes/edge, per-lane 4B edge rec + 16B h-load ----------
template<bool FULL>
static __device__ __forceinline__ void octo_step(const unsigned* __restrict__ h,
                                                 const unsigned* __restrict__ recs,
                                                 int e, int n, int q, int cg,
                                                 float acc[8]) {
    unsigned u;
    if (FULL) {
        u = recs[e + q];
    } else {
        u = recs[e + min(q, n - 1)];
    }
    const int sx = u & 0x1FFFF;
    float wq = (float)(u >> 17) * (1.f / 32767.f);
    if (!FULL) wq = (q < n) ? wq : 0.f;
    const uint4 hv = *(const uint4*)&h[(size_t)sx * 32 + cg * 4];
    const float2 f0 = bf2_to_f2(hv.x);
    const float2 f1 = bf2_to_f2(hv.y);
    const float2 f2 = bf2_to_f2(hv.z);
    const float2 f3 = bf2_to_f2(hv.w);
    acc[0] += wq * f0.x; acc[1] += wq * f0.y;
    acc[2] += wq * f1.x; acc[3] += wq * f1.y;
    acc[4] += wq * f2.x; acc[5] += wq * f2.y;
    acc[6] += wq * f3.x; acc[7] += wq * f3.y;
}

// ---------- Gather-aggregate (bf16 h): wave per node, 8 lanes per edge ----------
template<bool OUT_BF>
__global__ __launch_bounds__(256) void gather_octo(const unsigned* __restrict__ h, // bf162[N][32]
                                                   const int* __restrict__ row_ptr,
                                                   const unsigned* __restrict__ recs,
                                                   const float* __restrict__ bias,
                                                   void* __restrict__ outp) {
    const int node = (blockIdx.x * 256 + threadIdx.x) >> 6;
    if (node >= N_NODES) return;
    const int lane = threadIdx.x & 63;
    const int q  = lane >> 3;        // sub-wave: which of 8 edges
    const int cg = lane & 7;         // 16B chunk: cols 8*cg .. 8*cg+7
    const int beg = __builtin_amdgcn_readfirstlane(row_ptr[node]);
    const int end = __builtin_amdgcn_readfirstlane(row_ptr[node + 1]);
    float acc[8];
#pragma unroll
    for (int i = 0; i < 8; ++i) acc[i] = 0.f;
    int e = beg;
    for (; e + 16 <= end; e += 16) {           // 2 independent chains in flight
        octo_step<true>(h, recs, e, 8, q, cg, acc);
        octo_step<true>(h, recs, e + 8, 8, q, cg, acc);
    }
    if (e + 8 <= end) {
        octo_step<true>(h, recs, e, 8, q, cg, acc);
        e += 8;
    }
    if (e < end) {
        octo_step<false>(h, recs, e, end - e, q, cg, acc);
    }
#pragma unroll
    for (int i = 0; i < 8; ++i) {
        float a = acc[i];
        a += __shfl_xor(a, 8);
        a += __shfl_xor(a, 16);
        a += __shfl_xor(a, 32);
        acc[i] = a;
    }
    if (q == 0) {
        const float4 b0 = ((const float4*)bias)[cg * 2];
        const float4 b1 = ((const float4*)bias)[cg * 2 + 1];
        const float r0 = fmaxf(acc[0] + b0.x, 0.f);
        const float r1 = fmaxf(acc[1] + b0.y, 0.f);
        const float r2 = fmaxf(acc[2] + b0.z, 0.f);
        const float r3 = fmaxf(acc[3] + b0.w, 0.f);
        const float r4 = fmaxf(acc[4] + b1.x, 0.f);
        const float r5 = fmaxf(acc[5] + b1.y, 0.f);
        const float r6 = fmaxf(acc[6] + b1.z, 0.f);
        const float r7 = fmaxf(acc[7] + b1.w, 0.f);
        if (OUT_BF) {
            uint4 o;
            o.x = pack_bf2(r0, r1);
            o.y = pack_bf2(r2, r3);
            o.z = pack_bf2(r4, r5);
            o.w = pack_bf2(r6, r7);
            *(uint4*)&((unsigned*)outp)[(size_t)node * 32 + cg * 4] = o;
        } else {
            float* op = (float*)outp + (size_t)node * 64 + cg * 8;
            float4 o0; o0.x = r0; o0.y = r1; o0.z = r2; o0.w = r3;
            float4 o1; o1.x = r4; o1.y = r5; o1.z = r6; o1.w = r7;
            *(float4*)op = o0;
            *(float4*)(op + 4) = o1;
        }
    }
}

extern "C" void kernel_launch(void* const* d_in, const int* in_sizes, int n_in,
                              void* d_out, int out_size, void* d_ws, size_t ws_size,
                              hipStream_t stream) {
    const float* x    = (const float*)d_in[0];          // [100000, 128]
    const int*   eidx = (const int*)d_in[1];            // [2, 1600000]
    const float* mask = (const float*)d_in[2];          // [1600000]
    const float* W1   = (const float*)d_in[3];          // [128, 64]
    const float* b1   = (const float*)d_in[4];          // [64]
    const float* W2   = (const float*)d_in[5];          // [64, 64]
    const float* b2   = (const float*)d_in[6];          // [64]
    float* out = (float*)d_out;                          // [100000, 64]

    const int* src = eidx;
    const int* dst = eidx + N_EDGES;

    // workspace layout
    unsigned* hpre     = (unsigned*)d_ws;                       // 12.8 MB bf16 h
    unsigned* edge_sorted = (unsigned*)(hpre + (size_t)N_NODES * 32); // 6.4 MB (4B recs)
    int2*  coarse      = (int2*)(edge_sorted + N_EDGES);        // 12.8 MB (dead after s4)
    unsigned* h1bf     = (unsigned*)coarse;                     // alias: layer-1 output bf16
    int*   bh          = (int*)(coarse + N_EDGES);              // T2 ints
    int*   bh_ex       = bh + T2;
    int*   csum2       = bh_ex + T2;
    int*   coff2       = csum2 + NCH2;
    int*   row_ptr     = coff2 + NCH2;                          // 100001 ints
    short* wt1         = (short*)(row_ptr + N_NODES + 1);       // 16 KB
    short* wt2         = wt1 + 64 * 128;                        // 8 KB

    const int gemmBlocks = (N_NODES + 63) / 64;          // 1563
    const int gatherBlocks = (N_NODES * 64 + 255) / 256; // 25000

    prep_w<<<1, 256, 0, stream>>>(W1, W2, wt1, wt2);

    // ---- two-level counting sort by dst (once; reused by both layers) ----
    s1_hist<<<NBLK, 256, 0, stream>>>(dst, bh);
    scan_sums<<<NCH2, 256, 0, stream>>>(bh, csum2, T2);
    scan_off<<<1, 512, 0, stream>>>(csum2, coff2, NCH2);
    scan_apply<<<NCH2, 256, 0, stream>>>(bh, coff2, bh_ex, T2);
    s3_scatter<<<NBLK, 256, 0, stream>>>(src, dst, mask, bh_ex, coarse);
    s4_fine<<<NBUCKET, 256, 0, stream>>>(coarse, bh_ex, edge_sorted, row_ptr);

    // ---- Layer 1: h1 = relu(A @ bf16(x@W1) + b1), stored bf16 ----
    gemm_mfma<128, false><<<gemmBlocks, 256, 0, stream>>>(x, wt1, hpre);
    gather_octo<true><<<gatherBlocks, 256, 0, stream>>>(hpre, row_ptr, edge_sorted,
                                                        b1, h1bf);

    // ---- Layer 2: h2 = relu(A @ bf16(h1@W2) + b2), fp32 out ----
    gemm_mfma<64, true><<<gemmBlocks, 256, 0, stream>>>(h1bf, wt2, hpre);
    gather_octo<false><<<gatherBlocks, 256, 0, stream>>>(hpre, row_ptr, edge_sorted,
                                                         b2, out);
}

// Round 11
// 259.597 us; speedup vs baseline: 1.1065x; 1.1065x over previous
//
#include <hip/hip_runtime.h>
#include <hip/hip_bf16.h>

#define N_NODES 100000
#define N_EDGES 1600000
#define NBUCKET 391                 // ceil(100000 / 256) coarse buckets (dst >> 8)
#define NBLK 640                    // edge chunks (~2.5 blocks/CU)
#define CHUNK_E 2500                // 640 * 2500 = 1.6M exactly (div by 4 for int4)
#define T2 (NBUCKET * NBLK)         // 250240
#define NCH2 ((T2 + 511) / 512)     // 489 (<= 512 for single-block scan_off)

typedef short v8s __attribute__((ext_vector_type(8)));
typedef float v4f __attribute__((ext_vector_type(4)));

static __device__ __forceinline__ unsigned pack_bf2(float a, float b) {
    __hip_bfloat162 p = __float22bfloat162_rn(make_float2(a, b));
    return *reinterpret_cast<unsigned*>(&p);
}
static __device__ __forceinline__ float2 bf2_to_f2(unsigned u) {
    __hip_bfloat162 p = *reinterpret_cast<__hip_bfloat162*>(&u);
    return __bfloat1622float2(p);
}

// ---------- prep: transpose W -> Wt[n][k] bf16 (once, tiny) ----------
__global__ __launch_bounds__(256) void prep_w(const float* __restrict__ W1,
                                              const float* __restrict__ W2,
                                              short* __restrict__ wt1,   // [64][128]
                                              short* __restrict__ wt2) { // [64][64]
    const int t = threadIdx.x;
    for (int i = t; i < 64 * 128; i += 256) {
        const int c = i >> 7, k = i & 127;
        wt1[i] = (short)(pack_bf2(W1[k * 64 + c], 0.f) & 0xFFFF);
    }
    for (int i = t; i < 64 * 64; i += 256) {
        const int c = i >> 6, k = i & 63;
        wt2[i] = (short)(pack_bf2(W2[k * 64 + c], 0.f) & 0xFFFF);
    }
}

// ---------- MFMA GEMM: outp_bf16[M,64] = in[M,K] @ W[K,64] ----------
template<int K, bool IN_BF>
__global__ __launch_bounds__(256) void gemm_mfma(const void* __restrict__ in,
                                                 const short* __restrict__ wt,  // [64][K] bf16
                                                 unsigned* __restrict__ outp) { // bf162 [node][32]
    __shared__ unsigned xs[64][K / 2 + 4];
    __shared__ unsigned ws[64][K / 2 + 4];
    const int t = threadIdx.x;
    const int row0 = blockIdx.x * 64;
    {
        const uint2* g = (const uint2*)wt;
        for (int i = t; i < 64 * K / 4; i += 256) {
            const int r = i / (K / 4), cu = i % (K / 4);
            ((uint2*)&ws[r][0])[cu] = g[i];
        }
    }
    if (IN_BF) {
        const uint2* g = (const uint2*)in;
        for (int i = t; i < 64 * K / 4; i += 256) {
            const int r = i / (K / 4), cu = i % (K / 4);
            const int row = row0 + r;
            uint2 v = make_uint2(0u, 0u);
            if (row < N_NODES) v = g[(size_t)row * (K / 4) + cu];
            ((uint2*)&xs[r][0])[cu] = v;
        }
    } else {
        const float4* g = (const float4*)in;
        for (int i = t; i < 64 * K / 4; i += 256) {
            const int r = i / (K / 4), cu = i % (K / 4);
            const int row = row0 + r;
            uint2 v = make_uint2(0u, 0u);
            if (row < N_NODES) {
                float4 f = g[(size_t)row * (K / 4) + cu];
                v.x = pack_bf2(f.x, f.y);
                v.y = pack_bf2(f.z, f.w);
            }
            ((uint2*)&xs[r][0])[cu] = v;
        }
    }
    __syncthreads();
    const int w = t >> 6;
    const int lane = t & 63;
    const int l15 = lane & 15;
    const int quad = lane >> 4;
    v4f acc[4];
#pragma unroll
    for (int tt = 0; tt < 4; ++tt) acc[tt] = (v4f){0.f, 0.f, 0.f, 0.f};
#pragma unroll
    for (int k0 = 0; k0 < K; k0 += 32) {
        const int ku = k0 / 2 + quad * 4;
        const v8s xb = *(const v8s*)&xs[w * 16 + l15][ku];   // B: n=node
#pragma unroll
        for (int tt = 0; tt < 4; ++tt) {
            const v8s wa = *(const v8s*)&ws[16 * tt + l15][ku];  // A: m=out col
            acc[tt] = __builtin_amdgcn_mfma_f32_16x16x32_bf16(wa, xb, acc[tt], 0, 0, 0);
        }
    }
    const int node = row0 + w * 16 + l15;
    if (node < N_NODES) {
#pragma unroll
        for (int tt = 0; tt < 4; ++tt) {
            uint2 o;
            o.x = pack_bf2(acc[tt][0], acc[tt][1]);
            o.y = pack_bf2(acc[tt][2], acc[tt][3]);
            *(uint2*)&outp[(size_t)node * 32 + 8 * tt + 2 * quad] = o;
        }
    }
}

// ---------- S1: per-(block,bucket) coarse histogram (int4 reads) ----------
__global__ __launch_bounds__(256) void s1_hist(const int* __restrict__ dst,
                                               int* __restrict__ bh) {
    __shared__ int hist[NBUCKET];
    const int t = threadIdx.x;
    for (int i = t; i < NBUCKET; i += 256) hist[i] = 0;
    __syncthreads();
    const int4* d4 = (const int4*)(dst + blockIdx.x * CHUNK_E);
    for (int i = t; i < CHUNK_E / 4; i += 256) {
        const int4 v = d4[i];
        atomicAdd(&hist[v.x >> 8], 1);
        atomicAdd(&hist[v.y >> 8], 1);
        atomicAdd(&hist[v.z >> 8], 1);
        atomicAdd(&hist[v.w >> 8], 1);
    }
    __syncthreads();
    for (int i = t; i < NBUCKET; i += 256)
        bh[i * NBLK + blockIdx.x] = hist[i];
}

// ---------- S2: 3-phase exclusive scan of bh[T2] -> bh_ex ----------
__global__ __launch_bounds__(256) void scan_sums(const int* __restrict__ v,
                                                 int* __restrict__ csum, int n) {
    __shared__ int red[256];
    const int t = threadIdx.x;
    const int i0 = blockIdx.x * 512 + 2 * t;
    int a = (i0 < n) ? v[i0] : 0;
    int b = (i0 + 1 < n) ? v[i0 + 1] : 0;
    red[t] = a + b;
    __syncthreads();
    for (int off = 128; off > 0; off >>= 1) {
        if (t < off) red[t] += red[t + off];
        __syncthreads();
    }
    if (t == 0) csum[blockIdx.x] = red[0];
}

__global__ __launch_bounds__(512) void scan_off(const int* __restrict__ csum,
                                                int* __restrict__ coff, int nch) {
    __shared__ int part[512];
    const int t = threadIdx.x;
    int v = (t < nch) ? csum[t] : 0;
    part[t] = v;
    __syncthreads();
    for (int off = 1; off < 512; off <<= 1) {
        int u = (t >= off) ? part[t - off] : 0;
        __syncthreads();
        part[t] += u;
        __syncthreads();
    }
    if (t < nch) coff[t] = part[t] - v;   // exclusive
}

__global__ __launch_bounds__(256) void scan_apply(const int* __restrict__ v,
                                                  const int* __restrict__ coff,
                                                  int* __restrict__ vex, int n) {
    __shared__ int part[256];
    const int t = threadIdx.x;
    const int i0 = blockIdx.x * 512 + 2 * t;
    int a = (i0 < n) ? v[i0] : 0;
    int b = (i0 + 1 < n) ? v[i0 + 1] : 0;
    int pair = a + b;
    part[t] = pair;
    __syncthreads();
    for (int off = 1; off < 256; off <<= 1) {
        int u = (t >= off) ? part[t - off] : 0;
        __syncthreads();
        part[t] += u;
        __syncthreads();
    }
    const int e0 = coff[blockIdx.x] + part[t] - pair;
    if (i0 < n)     vex[i0] = e0;
    if (i0 + 1 < n) vex[i0 + 1] = e0 + a;
}

// ---------- S3: scatter edges into coarse buckets (int4/float4 reads) ----------
__global__ __launch_bounds__(256) void s3_scatter(const int* __restrict__ src,
                                                  const int* __restrict__ dst,
                                                  const float* __restrict__ w,
                                                  const int* __restrict__ bh_ex,
                                                  int2* __restrict__ coarse) {
    __shared__ int cur[NBUCKET];
    const int t = threadIdx.x;
    for (int i = t; i < NBUCKET; i += 256) cur[i] = bh_ex[i * NBLK + blockIdx.x];
    __syncthreads();
    const int e0 = blockIdx.x * CHUNK_E;
    const int4*   s4 = (const int4*)(src + e0);
    const int4*   d4 = (const int4*)(dst + e0);
    const float4* w4 = (const float4*)(w + e0);
    for (int i = t; i < CHUNK_E / 4; i += 256) {
        const int4 sv = s4[i];
        const int4 dv = d4[i];
        const float4 wv = w4[i];
        {
            const int pos = atomicAdd(&cur[dv.x >> 8], 1);
            coarse[pos] = make_int2(sv.x | ((dv.x & 255) << 17), __float_as_int(wv.x));
        }
        {
            const int pos = atomicAdd(&cur[dv.y >> 8], 1);
            coarse[pos] = make_int2(sv.y | ((dv.y & 255) << 17), __float_as_int(wv.y));
        }
        {
            const int pos = atomicAdd(&cur[dv.z >> 8], 1);
            coarse[pos] = make_int2(sv.z | ((dv.z & 255) << 17), __float_as_int(wv.z));
        }
        {
            const int pos = atomicAdd(&cur[dv.w >> 8], 1);
            coarse[pos] = make_int2(sv.w | ((dv.w & 255) << 17), __float_as_int(wv.w));
        }
    }
}

// ---------- S4: per-bucket fine sort (256 nodes, 1 bin/thread) + row_ptr ----------
// record = src(17 bits) | wq(15 bits, w*32767 fixed point)
__global__ __launch_bounds__(256) void s4_fine(const int2* __restrict__ coarse,
                                               const int* __restrict__ bh_ex,
                                               unsigned* __restrict__ edge_sorted,
                                               int* __restrict__ row_ptr) {
    __shared__ int hist[256];
    __shared__ int part[256];
    __shared__ int cursor[256];
    const int b = blockIdx.x;
    const int t = threadIdx.x;
    const int beg = bh_ex[b * NBLK];
    const int end = (b + 1 < NBUCKET) ? bh_ex[(b + 1) * NBLK] : N_EDGES;
    hist[t] = 0;
    __syncthreads();
    for (int i = beg + t; i < end; i += 256)
        atomicAdd(&hist[(coarse[i].x >> 17) & 255], 1);
    __syncthreads();
    const int v = hist[t];
    part[t] = v;
    __syncthreads();
    for (int off = 1; off < 256; off <<= 1) {
        int u = (t >= off) ? part[t - off] : 0;
        __syncthreads();
        part[t] += u;
        __syncthreads();
    }
    const int excl = beg + part[t] - v;
    cursor[t] = excl;
    const int node = b * 256 + t;
    if (node < N_NODES) row_ptr[node] = excl;
    if (b == NBUCKET - 1 && t == 0) row_ptr[N_NODES] = N_EDGES;
    __syncthreads();
    for (int i = beg + t; i < end; i += 256) {
        const int2 ev = coarse[i];
        const int f = (ev.x >> 17) & 255;
        const int pos = atomicAdd(&cursor[f], 1);
        unsigned wq = (unsigned)__float2uint_rn(__int_as_float(ev.y) * 32767.f);
        wq = min(wq, 32767u);
        edge_sorted[pos] = (unsigned)(ev.x & 0x1FFFF) | (wq << 17);
    }
}

// ---------- Gather step: 8 edges, 8 lanes/edge, per-lane 4B edge rec + 16B h-load ----------
template<bool FULL>
static __device__ __forceinline__ void octo_step(const unsigned* __restrict__ h,
                                                 const unsigned* __restrict__ recs,
                                                 int e, int n, int q, int cg,
                                                 float acc[8]) {
    unsigned u;
    if (FULL) {
        u = recs[e + q];
    } else {
        u = recs[e + min(q, n - 1)];
    }
    const int sx = u & 0x1FFFF;
    float wq = (float)(u >> 17) * (1.f / 32767.f);
    if (!FULL) wq = (q < n) ? wq : 0.f;
    const uint4 hv = *(const uint4*)&h[(size_t)sx * 32 + cg * 4];
    const float2 f0 = bf2_to_f2(hv.x);
    const float2 f1 = bf2_to_f2(hv.y);
    const float2 f2 = bf2_to_f2(hv.z);
    const float2 f3 = bf2_to_f2(hv.w);
    acc[0] += wq * f0.x; acc[1] += wq * f0.y;
    acc[2] += wq * f1.x; acc[3] += wq * f1.y;
    acc[4] += wq * f2.x; acc[5] += wq * f2.y;
    acc[6] += wq * f3.x; acc[7] += wq * f3.y;
}

// ---------- Gather-aggregate (bf16 h): wave per node, 8 lanes per edge ----------
// Epilogue: butterfly-with-rotation (7 shfl); every lane stores one column.
template<bool OUT_BF>
__global__ __launch_bounds__(256) void gather_octo(const unsigned* __restrict__ h, // bf162[N][32]
                                                   const int* __restrict__ row_ptr,
                                                   const unsigned* __restrict__ recs,
                                                   const float* __restrict__ bias,
                                                   void* __restrict__ outp) {
    const int node = (blockIdx.x * 256 + threadIdx.x) >> 6;
    if (node >= N_NODES) return;
    const int lane = threadIdx.x & 63;
    const int q  = lane >> 3;        // sub-wave: which of 8 edges
    const int cg = lane & 7;         // 16B chunk: cols 8*cg .. 8*cg+7
    const int beg = __builtin_amdgcn_readfirstlane(row_ptr[node]);
    const int end = __builtin_amdgcn_readfirstlane(row_ptr[node + 1]);
    float acc[8];
#pragma unroll
    for (int i = 0; i < 8; ++i) acc[i] = 0.f;
    int e = beg;
    for (; e + 16 <= end; e += 16) {           // 2 independent chains in flight
        octo_step<true>(h, recs, e, 8, q, cg, acc);
        octo_step<true>(h, recs, e + 8, 8, q, cg, acc);
    }
    if (e + 8 <= end) {
        octo_step<true>(h, recs, e, 8, q, cg, acc);
        e += 8;
    }
    if (e < end) {
        octo_step<false>(h, recs, e, end - e, q, cg, acc);
    }
    // stage 1: xor 8 (q bit0) — keep upper 4 accs if lane&8
    const bool h8 = (lane & 8) != 0;
    const float t0 = __shfl_xor(h8 ? acc[0] : acc[4], 8);
    const float t1 = __shfl_xor(h8 ? acc[1] : acc[5], 8);
    const float t2 = __shfl_xor(h8 ? acc[2] : acc[6], 8);
    const float t3 = __shfl_xor(h8 ? acc[3] : acc[7], 8);
    const float a0 = (h8 ? acc[4] : acc[0]) + t0;
    const float a1 = (h8 ? acc[5] : acc[1]) + t1;
    const float a2 = (h8 ? acc[6] : acc[2]) + t2;
    const float a3 = (h8 ? acc[7] : acc[3]) + t3;
    // stage 2: xor 16 (q bit1) — keep upper pair if lane&16
    const bool h16 = (lane & 16) != 0;
    const float u0 = __shfl_xor(h16 ? a0 : a2, 16);
    const float u1 = __shfl_xor(h16 ? a1 : a3, 16);
    const float b0 = (h16 ? a2 : a0) + u0;
    const float b1 = (h16 ? a3 : a1) + u1;
    // stage 3: xor 32 (q bit2) — keep upper if lane&32
    const bool h32 = (lane & 32) != 0;
    const float v0 = __shfl_xor(h32 ? b0 : b1, 32);
    const float rsum = (h32 ? b1 : b0) + v0;
    // lane holds col = 8*cg + (4*q0 + 2*q1 + q2)
    const int colq = ((q & 1) << 2) | (q & 2) | ((q >> 2) & 1);
    const int col = 8 * cg + colq;
    const float r = fmaxf(rsum + bias[col], 0.f);
    if (OUT_BF) {
        const unsigned p = pack_bf2(r, 0.f);
        ((short*)outp)[(size_t)node * 64 + col] = (short)(p & 0xFFFF);
    } else {
        ((float*)outp)[(size_t)node * 64 + col] = r;
    }
}

extern "C" void kernel_launch(void* const* d_in, const int* in_sizes, int n_in,
                              void* d_out, int out_size, void* d_ws, size_t ws_size,
                              hipStream_t stream) {
    const float* x    = (const float*)d_in[0];          // [100000, 128]
    const int*   eidx = (const int*)d_in[1];            // [2, 1600000]
    const float* mask = (const float*)d_in[2];          // [1600000]
    const float* W1   = (const float*)d_in[3];          // [128, 64]
    const float* b1   = (const float*)d_in[4];          // [64]
    const float* W2   = (const float*)d_in[5];          // [64, 64]
    const float* b2   = (const float*)d_in[6];          // [64]
    float* out = (float*)d_out;                          // [100000, 64]

    const int* src = eidx;
    const int* dst = eidx + N_EDGES;

    // workspace layout
    unsigned* hpre     = (unsigned*)d_ws;                       // 12.8 MB bf16 h
    unsigned* edge_sorted = (unsigned*)(hpre + (size_t)N_NODES * 32); // 6.4 MB (4B recs)
    int2*  coarse      = (int2*)(edge_sorted + N_EDGES);        // 12.8 MB (dead after s4)
    unsigned* h1bf     = (unsigned*)coarse;                     // alias: layer-1 output bf16
    int*   bh          = (int*)(coarse + N_EDGES);              // T2 ints
    int*   bh_ex       = bh + T2;
    int*   csum2       = bh_ex + T2;
    int*   coff2       = csum2 + NCH2;
    int*   row_ptr     = coff2 + NCH2;                          // 100001 ints
    short* wt1         = (short*)(row_ptr + N_NODES + 1);       // 16 KB
    short* wt2         = wt1 + 64 * 128;                        // 8 KB

    const int gemmBlocks = (N_NODES + 63) / 64;          // 1563
    const int gatherBlocks = (N_NODES * 64 + 255) / 256; // 25000

    prep_w<<<1, 256, 0, stream>>>(W1, W2, wt1, wt2);

    // ---- two-level counting sort by dst (once; reused by both layers) ----
    s1_hist<<<NBLK, 256, 0, stream>>>(dst, bh);
    scan_sums<<<NCH2, 256, 0, stream>>>(bh, csum2, T2);
    scan_off<<<1, 512, 0, stream>>>(csum2, coff2, NCH2);
    scan_apply<<<NCH2, 256, 0, stream>>>(bh, coff2, bh_ex, T2);
    s3_scatter<<<NBLK, 256, 0, stream>>>(src, dst, mask, bh_ex, coarse);
    s4_fine<<<NBUCKET, 256, 0, stream>>>(coarse, bh_ex, edge_sorted, row_ptr);

    // ---- Layer 1: h1 = relu(A @ bf16(x@W1) + b1), stored bf16 ----
    gemm_mfma<128, false><<<gemmBlocks, 256, 0, stream>>>(x, wt1, hpre);
    gather_octo<true><<<gatherBlocks, 256, 0, stream>>>(hpre, row_ptr, edge_sorted,
                                                        b1, h1bf);

    // ---- Layer 2: h2 = relu(A @ bf16(h1@W2) + b2), fp32 out ----
    gemm_mfma<64, true><<<gemmBlocks, 256, 0, stream>>>(h1bf, wt2, hpre);
    gather_octo<false><<<gatherBlocks, 256, 0, stream>>>(hpre, row_ptr, edge_sorted,
                                                         b2, out);
}